// Round 14
// baseline (187.772 us; speedup 1.0000x reference)
//
#include <hip/hip_runtime.h>
#include <math.h>

#define C 64
#define BN 128              // nodes per destination bucket
#define BSHIFT 7            // log2(BN)
#define NPART 1024          // partition blocks
#define EPB_CAP 1600        // LDS staging capacity per partition block
#define SCAP 4096           // LDS staging capacity per sort bucket (mean 2046, ~45 sigma)
#define RMASK ((1 << 20) - 1)

typedef unsigned int uint;
typedef unsigned short ushort;

__device__ __forceinline__ float sigf(float x) { return 1.0f / (1.0f + __expf(-x)); }

// round-to-nearest-even f32 -> bf16 bits (values are finite, no NaN handling)
__device__ __forceinline__ ushort f2bf(float f) {
    uint u = __float_as_uint(f);
    return (ushort)((u + 0x7fffu + ((u >> 16) & 1u)) >> 16);
}

// fma 8 packed bf16 (uint4) into acc[8]
__device__ __forceinline__ void bf8fma(uint4 u, float nn, float* a) {
    a[0] = fmaf(__uint_as_float(u.x << 16),          nn, a[0]);
    a[1] = fmaf(__uint_as_float(u.x & 0xffff0000u),  nn, a[1]);
    a[2] = fmaf(__uint_as_float(u.y << 16),          nn, a[2]);
    a[3] = fmaf(__uint_as_float(u.y & 0xffff0000u),  nn, a[3]);
    a[4] = fmaf(__uint_as_float(u.z << 16),          nn, a[4]);
    a[5] = fmaf(__uint_as_float(u.z & 0xffff0000u),  nn, a[5]);
    a[6] = fmaf(__uint_as_float(u.w << 16),          nn, a[6]);
    a[7] = fmaf(__uint_as_float(u.w & 0xffff0000u),  nn, a[7]);
}

// in-LDS spine: bbl[0..nbuck-1] = exclusive scan of btot (512 threads, 2/thread)
__device__ __forceinline__ void spine_scan(
    const int* __restrict__ btot, int* bbl, int* wsum, int nbuck, int t)
{
    int lane = t & 63, wid = t >> 6;
    int i0 = 2 * t, i1 = 2 * t + 1;
    int v0 = (i0 < nbuck) ? btot[i0] : 0;
    int v1 = (i1 < nbuck) ? btot[i1] : 0;
    int s = v0 + v1;
    int x = s;
    #pragma unroll
    for (int d = 1; d < 64; d <<= 1) {
        int y = __shfl_up(x, d, 64);
        if (lane >= d) x += y;
    }
    if (lane == 63) wsum[wid] = x;
    __syncthreads();
    if (t == 0) {
        int run = 0;
        #pragma unroll
        for (int w = 0; w < 8; ++w) { int z = wsum[w]; wsum[w] = run; run += z; }
    }
    __syncthreads();
    int excl = x - s + wsum[wid];
    bbl[i0] = excl;
    bbl[i1] = excl + v0;
}

// ---- Kernel 1: hist (blocks < NPART) + LSTM weight (blocks >= NPART) ------
__global__ __launch_bounds__(512) void hist_lstm_kernel(
    const int* __restrict__ col, int* __restrict__ hist,
    int E, int nbuck, int epb,
    const float* __restrict__ cw,
    const float* __restrict__ wf, const float* __restrict__ bif, const float* __restrict__ bhf,
    const float* __restrict__ wb, const float* __restrict__ bib, const float* __restrict__ bhb,
    float* __restrict__ W)
{
    int b = blockIdx.x, t = threadIdx.x;

    if (b >= NPART) {
        int tid = (b - NPART) * 512 + t;       // 0..4095
        if (tid >= C * C) return;
        int r = tid >> 6, c = tid & 63;
        const float* x = cw + r * C;
        const float* f_i = wf + (0 * C + c) * C;
        const float* f_g = wf + (2 * C + c) * C;
        const float* f_o = wf + (3 * C + c) * C;
        const float* b_i = wb + (0 * C + c) * C;
        const float* b_g = wb + (2 * C + c) * C;
        const float* b_o = wb + (3 * C + c) * C;

        float zif = 0.f, zgf = 0.f, zof = 0.f, zib = 0.f, zgb = 0.f, zob = 0.f;
        #pragma unroll
        for (int k = 0; k < C; ++k) {
            float xv = x[k];
            zif = fmaf(xv, f_i[k], zif);
            zgf = fmaf(xv, f_g[k], zgf);
            zof = fmaf(xv, f_o[k], zof);
            zib = fmaf(xv, b_i[k], zib);
            zgb = fmaf(xv, b_g[k], zgb);
            zob = fmaf(xv, b_o[k], zob);
        }
        zif += bif[0 * C + c] + bhf[0 * C + c];
        zgf += bif[2 * C + c] + bhf[2 * C + c];
        zof += bif[3 * C + c] + bhf[3 * C + c];
        zib += bib[0 * C + c] + bhb[0 * C + c];
        zgb += bib[2 * C + c] + bhb[2 * C + c];
        zob += bib[3 * C + c] + bhb[3 * C + c];

        float cf = sigf(zif) * tanhf(zgf);
        float hf = sigf(zof) * tanhf(cf);
        float cb = sigf(zib) * tanhf(zgb);
        float hb = sigf(zob) * tanhf(cb);
        W[tid] = fmaxf(hf, hb);
        return;
    }

    __shared__ int h[1024];
    for (int i = t; i < nbuck; i += 512) h[i] = 0;
    __syncthreads();
    int base = b * epb;
    int end = min(base + epb, E);
    for (int e = base + t; e < end; e += 512)
        atomicAdd(&h[col[e] >> BSHIFT], 1);
    __syncthreads();
    for (int i = t; i < nbuck; i += 512) hist[b * nbuck + i] = h[i];
}

// ---- Kernel 2: per-bucket exclusive scan over blocks (parallel) -----------
// hist[b][k] becomes exclusive prefix (over blocks) for bucket k; btot[k]=total.
__global__ __launch_bounds__(1024) void scan_blocks_kernel(
    int* __restrict__ hist, int* __restrict__ btot, int nbuck)
{
    __shared__ int wsum[16];
    int k = blockIdx.x;
    int b = threadIdx.x;
    int v = hist[b * nbuck + k];
    int lane = b & 63, wid = b >> 6;
    int x = v;
    #pragma unroll
    for (int d = 1; d < 64; d <<= 1) {
        int y = __shfl_up(x, d, 64);
        if (lane >= d) x += y;
    }
    if (lane == 63) wsum[wid] = x;
    __syncthreads();
    if (b == 0) {
        int run = 0;
        #pragma unroll
        for (int w = 0; w < 16; ++w) { int z = wsum[w]; wsum[w] = run; run += z; }
    }
    __syncthreads();
    int excl = x - v + wsum[wid];
    hist[b * nbuck + k] = excl;
    if (b == NPART - 1) btot[k] = excl + v;
}

// ---- Kernel 3: partition — no recount (bins derived from scanned hist) ----
__global__ __launch_bounds__(512) void partition_kernel(
    const int* __restrict__ row, const int* __restrict__ col,
    const float* __restrict__ ew, const int* __restrict__ hist,
    const int* __restrict__ btot, int2* __restrict__ payload,
    int E, int nbuck, int epb)
{
    __shared__ int bins[1024];
    __shared__ int base[1024];
    __shared__ int cur[1024];
    __shared__ int hbase[1024];
    __shared__ int bbl[1024];
    __shared__ int2 lpay[EPB_CAP];      // 12.8 KB
    __shared__ ushort karr[EPB_CAP];    // 3.2 KB
    __shared__ int wsum[8];

    int t = threadIdx.x, b = blockIdx.x;
    int lane = t & 63, wid = t >> 6;

    spine_scan(btot, bbl, wsum, nbuck, t);

    // bins[k] = this block's count for bucket k, derived from scanned hist
    for (int i = t; i < 1024; i += 512) {
        int hb = (i < nbuck) ? hist[b * nbuck + i] : 0;
        int hn = 0;
        if (i < nbuck)
            hn = (b < NPART - 1) ? hist[(b + 1) * nbuck + i] : btot[i];
        hbase[i] = hb;
        bins[i] = hn - hb;
    }
    __syncthreads();

    // local exclusive scan of bins
    {
        int a = bins[2 * t], b2 = bins[2 * t + 1];
        int s = a + b2;
        int x = s;
        #pragma unroll
        for (int d = 1; d < 64; d <<= 1) {
            int y = __shfl_up(x, d, 64);
            if (lane >= d) x += y;
        }
        if (lane == 63) wsum[wid] = x;
        __syncthreads();
        if (t == 0) {
            int run = 0;
            #pragma unroll
            for (int w = 0; w < 8; ++w) { int z = wsum[w]; wsum[w] = run; run += z; }
        }
        __syncthreads();
        int excl = x - s + wsum[wid];
        base[2 * t] = excl;
        base[2 * t + 1] = excl + a;
        cur[2 * t] = excl;
        cur[2 * t + 1] = excl + a;
    }
    __syncthreads();

    int e0 = b * epb;
    int e1 = min(e0 + epb, E);
    for (int e = e0 + t; e < e1; e += 512) {
        int c = col[e];
        int k = c >> BSHIFT;
        int pos = atomicAdd(&cur[k], 1);
        lpay[pos] = make_int2(row[e] | ((c & (BN - 1)) << 20),
                              __float_as_int(ew[e]));
        karr[pos] = (ushort)k;
    }
    __syncthreads();

    int tot = e1 - e0;
    for (int i = t; i < tot; i += 512) {
        int k = karr[i];
        int dst = bbl[k] + hbase[k] + (i - base[k]);
        payload[dst] = lpay[i];
    }
}

// ---- Kernel 4: deg_bins — per-bucket weighted degree -> dinv, bin counts --
__global__ __launch_bounds__(512) void deg_bins_kernel(
    const int2* __restrict__ payload, const int* __restrict__ btot,
    float* __restrict__ dinv, int* __restrict__ binsg, int N, int nbuck)
{
    __shared__ int bbl[1024];
    __shared__ int wsum[8];
    __shared__ int bin[BN];
    __shared__ float degl[BN];
    int t = threadIdx.x, k = blockIdx.x;

    spine_scan(btot, bbl, wsum, nbuck, t);
    if (t < BN) { bin[t] = 0; degl[t] = 0.f; }
    __syncthreads();

    int e0 = bbl[k], e1 = e0 + btot[k];
    for (int e = e0 + t; e < e1; e += 512) {
        int2 p = payload[e];
        int ld = p.x >> 20;
        atomicAdd(&bin[ld], 1);
        atomicAdd(&degl[ld], __int_as_float(p.y));
    }
    __syncthreads();

    if (t < BN) {
        int n = k * BN + t;
        if (n < N) dinv[n] = rsqrtf(degl[t] + 1.0f);   // +1 self-loop weight
        binsg[k * BN + t] = bin[t];
    }
}

// ---- Kernel 5: Xw' = bf16( dinv ⊙ (X @ W) )  (64 rows/block, 512 thr) -----
__global__ __launch_bounds__(512) void gemm_xw_kernel(
    const float* __restrict__ X, const float* __restrict__ W,
    const float* __restrict__ dinv, ushort* __restrict__ Y, int N)
{
    __shared__ float Wl[C * C];         // 16 KB
    __shared__ float xl[64][C];         // 16 KB
    int t = threadIdx.x;
    #pragma unroll
    for (int i = 0; i < 2; ++i)
        *(float4*)(Wl + 4 * (t + i * 512)) = *(const float4*)(W + 4 * (t + i * 512));

    int n0 = blockIdx.x * 64;
    #pragma unroll
    for (int i = 0; i < 2; ++i) {
        int idx = t + i * 512;            // 0..1023 : (row, float4-group)
        int rr = idx >> 4, cc = (idx & 15) << 2;
        int n = n0 + rr;
        float4 v = (n < N) ? *(const float4*)(X + (size_t)n * C + cc)
                           : make_float4(0.f, 0.f, 0.f, 0.f);
        *(float4*)(&xl[rr][cc]) = v;
    }
    __syncthreads();

    int c = t & 63, rb = (t >> 6) * 8;    // 8 waves x 8 rows = 64 rows
    float acc[8] = {0.f, 0.f, 0.f, 0.f, 0.f, 0.f, 0.f, 0.f};
    for (int k = 0; k < C; ++k) {
        float w = Wl[k * C + c];
        #pragma unroll
        for (int q = 0; q < 8; ++q) acc[q] = fmaf(xl[rb + q][k], w, acc[q]);
    }
    #pragma unroll
    for (int q = 0; q < 8; ++q) {
        int n = n0 + rb + q;
        if (n < N) Y[(size_t)n * C + c] = f2bf(acc[q] * dinv[n]);  // fold dinv[src]
    }
}

// ---- Kernel 6: sort_reduce — LDS counting sort + gather-reduce fused ------
__global__ __launch_bounds__(512) void sort_reduce_kernel(
    const int2* __restrict__ payload, const int* __restrict__ btot,
    const int* __restrict__ binsg, const float* __restrict__ dinv,
    const ushort* __restrict__ Xw,
    const float* __restrict__ ne, const float* __restrict__ ce,
    ushort* __restrict__ tmpb, int N, int nbuck)
{
    __shared__ int bbl[1024];
    __shared__ int wsum[8];
    __shared__ int bin[BN];
    __shared__ int bbase[BN];
    __shared__ int cur[BN];
    __shared__ float dinvl[BN];
    __shared__ int2 spay[SCAP];         // 32 KB
    int t = threadIdx.x, k = blockIdx.x;

    spine_scan(btot, bbl, wsum, nbuck, t);

    if (t < BN) {
        int n = k * BN + t;
        bin[t] = binsg[k * BN + t];
        dinvl[t] = (n < N) ? dinv[n] : 0.f;
    }
    __syncthreads();

    // exclusive scan of bin[0..127] in wave 0 (2 bins per lane)
    if (t < 64) {
        int a = bin[2 * t], b2 = bin[2 * t + 1];
        int s = a + b2;
        int x = s;
        #pragma unroll
        for (int d = 1; d < 64; d <<= 1) {
            int y = __shfl_up(x, d, 64);
            if (t >= d) x += y;
        }
        int excl = x - s;
        bbase[2 * t] = excl;
        bbase[2 * t + 1] = excl + a;
    }
    __syncthreads();
    if (t < BN) cur[t] = bbase[t];
    __syncthreads();

    int e0 = bbl[k];
    int tot = btot[k];
    bool fits = (tot <= SCAP);

    if (fits) {
        for (int e = e0 + t; e < e0 + tot; e += 512) {
            int2 p = payload[e];
            int ld = p.x >> 20;
            int pos = atomicAdd(&cur[ld], 1);
            spay[pos] = make_int2(p.x & RMASK,
                                  __float_as_int(__int_as_float(p.y) * dinvl[ld]));
        }
    }
    __syncthreads();

    // ---- reduce phase: 2 passes x 64 nodes, 8 lanes/node ----
    int lg = t >> 3;                      // node group 0..63
    int cs = (t & 7) << 3;                // channel offset (8 channels/lane)
    #pragma unroll
    for (int pass = 0; pass < 2; ++pass) {
        int ln = lg + pass * 64;          // local node 0..127
        int n = k * BN + ln;
        if (n >= N) continue;

        float a[8] = {0.f, 0.f, 0.f, 0.f, 0.f, 0.f, 0.f, 0.f};
        if (fits) {
            int j = bbase[ln], cnt = bin[ln];
            while (cnt >= 4) {
                int2 p0 = spay[j];
                int2 p1 = spay[j + 1];
                int2 p2 = spay[j + 2];
                int2 p3 = spay[j + 3];
                uint4 u0 = *(const uint4*)(Xw + (size_t)p0.x * C + cs);
                uint4 u1 = *(const uint4*)(Xw + (size_t)p1.x * C + cs);
                uint4 u2 = *(const uint4*)(Xw + (size_t)p2.x * C + cs);
                uint4 u3 = *(const uint4*)(Xw + (size_t)p3.x * C + cs);
                bf8fma(u0, __int_as_float(p0.y), a);
                bf8fma(u1, __int_as_float(p1.y), a);
                bf8fma(u2, __int_as_float(p2.y), a);
                bf8fma(u3, __int_as_float(p3.y), a);
                j += 4; cnt -= 4;
            }
            while (cnt > 0) {
                int2 pl = spay[j];
                uint4 u = *(const uint4*)(Xw + (size_t)pl.x * C + cs);
                bf8fma(u, __int_as_float(pl.y), a);
                ++j; --cnt;
            }
        } else {
            // correctness fallback (tot > SCAP never occurs for this data)
            for (int e = e0; e < e0 + tot; ++e) {
                int2 p = payload[e];
                if ((p.x >> 20) == ln) {
                    float nn = __int_as_float(p.y) * dinvl[ln];
                    uint4 u = *(const uint4*)(Xw + (size_t)(p.x & RMASK) * C + cs);
                    bf8fma(u, nn, a);
                }
            }
        }

        float di = dinvl[ln];
        size_t o = (size_t)n * C + cs;
        uint4 ux = *(const uint4*)(Xw + o);     // Xw' = dinv[n]*(X@W)[n]
        bf8fma(ux, di, a);
        const float4 nv0 = *(const float4*)(ne + o);
        const float4 nv1 = *(const float4*)(ne + o + 4);
        const float4 cv0 = *(const float4*)(ce + o);
        const float4 cv1 = *(const float4*)(ce + o + 4);
        a[0] += nv0.x + cv0.x;  a[1] += nv0.y + cv0.y;
        a[2] += nv0.z + cv0.z;  a[3] += nv0.w + cv0.w;
        a[4] += nv1.x + cv1.x;  a[5] += nv1.y + cv1.y;
        a[6] += nv1.z + cv1.z;  a[7] += nv1.w + cv1.w;

        uint4 w;
        w.x = (uint)f2bf(a[0]) | ((uint)f2bf(a[1]) << 16);
        w.y = (uint)f2bf(a[2]) | ((uint)f2bf(a[3]) << 16);
        w.z = (uint)f2bf(a[4]) | ((uint)f2bf(a[5]) << 16);
        w.w = (uint)f2bf(a[6]) | ((uint)f2bf(a[7]) << 16);
        *(uint4*)(tmpb + o) = w;
    }
}

// ---- Kernel 7: out = tmp @ fW^T + fb  (64 rows/block, 512 thr, bf16 in) ---
__global__ __launch_bounds__(512) void fusion_kernel(
    const ushort* __restrict__ tmpb, const float* __restrict__ fW,
    const float* __restrict__ fb, float* __restrict__ out, int N)
{
    __shared__ float Wt[C][C + 1];   // 16.25 KB, Wt[k][j] = fW[j*C+k]
    __shared__ float tl[64][C];      // 16 KB
    int t = threadIdx.x;
    #pragma unroll
    for (int i = 0; i < 8; ++i) {
        int idx = t + i * 512;
        Wt[idx & 63][idx >> 6] = fW[idx];
    }
    int n0 = blockIdx.x * 64;
    {
        int rr = t >> 3, cs = (t & 7) << 3;   // 512 thr x 8 ch = 64 rows
        int n = n0 + rr;
        uint4 u = (n < N) ? *(const uint4*)(tmpb + (size_t)n * C + cs)
                          : make_uint4(0u, 0u, 0u, 0u);
        tl[rr][cs + 0] = __uint_as_float(u.x << 16);
        tl[rr][cs + 1] = __uint_as_float(u.x & 0xffff0000u);
        tl[rr][cs + 2] = __uint_as_float(u.y << 16);
        tl[rr][cs + 3] = __uint_as_float(u.y & 0xffff0000u);
        tl[rr][cs + 4] = __uint_as_float(u.z << 16);
        tl[rr][cs + 5] = __uint_as_float(u.z & 0xffff0000u);
        tl[rr][cs + 6] = __uint_as_float(u.w << 16);
        tl[rr][cs + 7] = __uint_as_float(u.w & 0xffff0000u);
    }
    __syncthreads();

    int j = t & 63, rb = (t >> 6) * 8;        // 8 waves x 8 rows = 64 rows
    float bj = fb[j];
    float acc[8] = {bj, bj, bj, bj, bj, bj, bj, bj};
    for (int k = 0; k < C; ++k) {
        float w = Wt[k][j];
        #pragma unroll
        for (int q = 0; q < 8; ++q) acc[q] = fmaf(tl[rb + q][k], w, acc[q]);
    }
    #pragma unroll
    for (int q = 0; q < 8; ++q) {
        int n = n0 + rb + q;
        if (n < N) out[(size_t)n * C + j] = acc[q];
    }
}

extern "C" void kernel_launch(void* const* d_in, const int* in_sizes, int n_in,
                              void* d_out, int out_size, void* d_ws, size_t ws_size,
                              hipStream_t stream)
{
    const float* X        = (const float*)d_in[0];
    const int*   ei       = (const int*)d_in[1];
    const float* ew       = (const float*)d_in[2];
    const float* node_emb = (const float*)d_in[3];
    const float* com_emb  = (const float*)d_in[4];
    const float* cw       = (const float*)d_in[5];
    const float* w_ih_f   = (const float*)d_in[6];
    const float* b_ih_f   = (const float*)d_in[7];
    const float* b_hh_f   = (const float*)d_in[8];
    const float* w_ih_b   = (const float*)d_in[9];
    const float* b_ih_b   = (const float*)d_in[10];
    const float* b_hh_b   = (const float*)d_in[11];
    const float* fW       = (const float*)d_in[12];
    const float* fb       = (const float*)d_in[13];
    float* out = (float*)d_out;

    const int N = in_sizes[0] / C;
    const int E = in_sizes[2];
    const int* row = ei;               // edge_index[0]
    const int* col = ei + E;           // edge_index[1]
    const int nbuck = (N + BN - 1) / BN;        // 782 (<= 1024 by design)
    const int epb = (E + NPART - 1) / NPART;    // 1563 <= EPB_CAP

    // ---- workspace layout ----
    char* wsb = (char*)d_ws;
    size_t o = 0;
    auto alloc = [&](size_t bytes) { void* p = wsb + o; o = (o + bytes + 15) & ~(size_t)15; return p; };
    float* W     = (float*)alloc((size_t)C * C * sizeof(float));        // 16 KB
    float* dinv  = (float*)alloc((size_t)N * sizeof(float));            // 400 KB
    int*   btot  = (int*)  alloc((size_t)(nbuck + 1) * sizeof(int));    // 3 KB
    int*   binsg = (int*)  alloc((size_t)nbuck * BN * sizeof(int));     // 400 KB
    int2*  payload = (int2*)alloc((size_t)E * sizeof(int2));            // 12.8 MB
    int*   hist  = (int*)  alloc((size_t)NPART * nbuck * sizeof(int));  // 3.2 MB
    ushort* tmpb = (ushort*)alloc((size_t)N * C * sizeof(ushort));      // 12.8 MB
    ushort* Xw   = (ushort*)out;   // d_out holds bf16 Xw' until fusion overwrites

    hist_lstm_kernel<<<NPART + (C * C + 511) / 512, 512, 0, stream>>>(
        col, hist, E, nbuck, epb,
        cw, w_ih_f, b_ih_f, b_hh_f, w_ih_b, b_ih_b, b_hh_b, W);

    scan_blocks_kernel<<<nbuck, NPART, 0, stream>>>(hist, btot, nbuck);

    partition_kernel<<<NPART, 512, 0, stream>>>(
        row, col, ew, hist, btot, payload, E, nbuck, epb);

    deg_bins_kernel<<<nbuck, 512, 0, stream>>>(
        payload, btot, dinv, binsg, N, nbuck);

    gemm_xw_kernel<<<(N + 63) / 64, 512, 0, stream>>>(X, W, dinv, Xw, N);

    sort_reduce_kernel<<<nbuck, 512, 0, stream>>>(
        payload, btot, binsg, dinv, Xw, node_emb, com_emb, tmpb, N, nbuck);

    fusion_kernel<<<(N + 63) / 64, 512, 0, stream>>>(tmpb, fW, fb, out, N);
}

// Round 15
// 146.252 us; speedup vs baseline: 1.2839x; 1.2839x over previous
//
#include <hip/hip_runtime.h>
#include <math.h>

#define C 64
#define BN 128              // nodes per destination bucket
#define BSHIFT 7            // log2(BN)
#define NPART 512           // partition blocks
#define EPB_CAP 3200        // LDS staging capacity per partition block
#define SCAP 4096           // LDS staging capacity per sort bucket (mean 2046, ~45 sigma)
#define RMASK ((1 << 20) - 1)
#define LCOLS 4             // output columns per LSTM block

typedef unsigned int uint;
typedef unsigned short ushort;

__device__ __forceinline__ float sigf(float x) { return 1.0f / (1.0f + __expf(-x)); }

// round-to-nearest-even f32 -> bf16 bits (values are finite, no NaN handling)
__device__ __forceinline__ ushort f2bf(float f) {
    uint u = __float_as_uint(f);
    return (ushort)((u + 0x7fffu + ((u >> 16) & 1u)) >> 16);
}

// fma 8 packed bf16 (uint4) into acc[8]
__device__ __forceinline__ void bf8fma(uint4 u, float nn, float* a) {
    a[0] = fmaf(__uint_as_float(u.x << 16),          nn, a[0]);
    a[1] = fmaf(__uint_as_float(u.x & 0xffff0000u),  nn, a[1]);
    a[2] = fmaf(__uint_as_float(u.y << 16),          nn, a[2]);
    a[3] = fmaf(__uint_as_float(u.y & 0xffff0000u),  nn, a[3]);
    a[4] = fmaf(__uint_as_float(u.z << 16),          nn, a[4]);
    a[5] = fmaf(__uint_as_float(u.z & 0xffff0000u),  nn, a[5]);
    a[6] = fmaf(__uint_as_float(u.w << 16),          nn, a[6]);
    a[7] = fmaf(__uint_as_float(u.w & 0xffff0000u),  nn, a[7]);
}

// in-LDS spine: bbl[0..nbuck-1] = exclusive scan of btot (512 threads, 2/thread)
__device__ __forceinline__ void spine_scan(
    const int* __restrict__ btot, int* bbl, int* wsum, int nbuck, int t)
{
    int lane = t & 63, wid = t >> 6;
    int i0 = 2 * t, i1 = 2 * t + 1;
    int v0 = (i0 < nbuck) ? btot[i0] : 0;
    int v1 = (i1 < nbuck) ? btot[i1] : 0;
    int s = v0 + v1;
    int x = s;
    #pragma unroll
    for (int d = 1; d < 64; d <<= 1) {
        int y = __shfl_up(x, d, 64);
        if (lane >= d) x += y;
    }
    if (lane == 63) wsum[wid] = x;
    __syncthreads();
    if (t == 0) {
        int run = 0;
        #pragma unroll
        for (int w = 0; w < 8; ++w) { int z = wsum[w]; wsum[w] = run; run += z; }
    }
    __syncthreads();
    int excl = x - s + wsum[wid];
    bbl[i0] = excl;
    bbl[i1] = excl + v0;
}

// ---- Kernel 1: LSTM weight, LDS-cooperative (coalesced loads) -------------
// Block b computes W[:, c0..c0+3], c0 = b*LCOLS. Stages conv_weight and the
// 6 needed gate-weight rows in LDS (coalesced), computes dot products from
// LDS (padded stride 65: conflict-free broadcast).
__global__ __launch_bounds__(256) void lstm_w_kernel(
    const float* __restrict__ cw,
    const float* __restrict__ wf, const float* __restrict__ bif, const float* __restrict__ bhf,
    const float* __restrict__ wb, const float* __restrict__ bib, const float* __restrict__ bhb,
    float* __restrict__ W)
{
    __shared__ float cwl[C][C + 1];        // 16.25 KB
    __shared__ float wl[6][LCOLS][C + 1];  // ~6.1 KB
    int t = threadIdx.x, b = blockIdx.x;
    int c0 = b * LCOLS;

    for (int m = t; m < C * C; m += 256)
        cwl[m >> 6][m & 63] = cw[m];

    // gate row offsets within [4C, C] weights: i=0, g=2C, o=3C (f unused, c0=0)
    for (int m = t; m < 6 * LCOLS * C; m += 256) {
        int mat = m >> 8;               // /(LCOLS*C)=256
        int idx = m & 255;
        int col = idx >> 6, k = idx & 63;
        int gofs = (mat % 3 == 0) ? 0 : ((mat % 3 == 1) ? 2 * C : 3 * C);
        const float* src = (mat < 3) ? wf : wb;
        wl[mat][col][k] = src[(gofs + c0 + col) * C + k];
    }
    __syncthreads();

    int r = t >> 2, cl = t & 3;
    int c = c0 + cl;
    float zif = 0.f, zgf = 0.f, zof = 0.f, zib = 0.f, zgb = 0.f, zob = 0.f;
    #pragma unroll
    for (int k = 0; k < C; ++k) {
        float xv = cwl[r][k];
        zif = fmaf(xv, wl[0][cl][k], zif);
        zgf = fmaf(xv, wl[1][cl][k], zgf);
        zof = fmaf(xv, wl[2][cl][k], zof);
        zib = fmaf(xv, wl[3][cl][k], zib);
        zgb = fmaf(xv, wl[4][cl][k], zgb);
        zob = fmaf(xv, wl[5][cl][k], zob);
    }
    zif += bif[0 * C + c] + bhf[0 * C + c];
    zgf += bif[2 * C + c] + bhf[2 * C + c];
    zof += bif[3 * C + c] + bhf[3 * C + c];
    zib += bib[0 * C + c] + bhb[0 * C + c];
    zgb += bib[2 * C + c] + bhb[2 * C + c];
    zob += bib[3 * C + c] + bhb[3 * C + c];

    float cf = sigf(zif) * tanhf(zgf);
    float hf = sigf(zof) * tanhf(cf);
    float cb = sigf(zib) * tanhf(zgb);
    float hb = sigf(zob) * tanhf(cb);
    W[r * C + c] = fmaxf(hf, hb);
}

// ---- Kernel 2: per-block bucket histogram (LDS atomics only) --------------
__global__ __launch_bounds__(256) void hist_kernel(
    const int* __restrict__ col, int* __restrict__ hist,
    int E, int nbuck, int epb)
{
    __shared__ int h[1024];
    int t = threadIdx.x, b = blockIdx.x;
    for (int i = t; i < nbuck; i += 256) h[i] = 0;
    __syncthreads();
    int base = b * epb;
    int end = min(base + epb, E);
    for (int e = base + t; e < end; e += 256)
        atomicAdd(&h[col[e] >> BSHIFT], 1);
    __syncthreads();
    for (int i = t; i < nbuck; i += 256) hist[b * nbuck + i] = h[i];
}

// ---- Kernel 3: per-bucket exclusive scan over blocks (parallel) -----------
__global__ __launch_bounds__(512) void scan_blocks_kernel(
    int* __restrict__ hist, int* __restrict__ btot, int nbuck)
{
    __shared__ int wsum[8];
    int k = blockIdx.x;
    int b = threadIdx.x;
    int v = hist[b * nbuck + k];
    int lane = b & 63, wid = b >> 6;
    int x = v;
    #pragma unroll
    for (int d = 1; d < 64; d <<= 1) {
        int y = __shfl_up(x, d, 64);
        if (lane >= d) x += y;
    }
    if (lane == 63) wsum[wid] = x;
    __syncthreads();
    if (b == 0) {
        int run = 0;
        #pragma unroll
        for (int w = 0; w < 8; ++w) { int z = wsum[w]; wsum[w] = run; run += z; }
    }
    __syncthreads();
    int excl = x - v + wsum[wid];
    hist[b * nbuck + k] = excl;
    if (b == NPART - 1) btot[k] = excl + v;
}

// ---- Kernel 4: partition — no recount (bins derived from scanned hist) ----
__global__ __launch_bounds__(512) void partition_kernel(
    const int* __restrict__ row, const int* __restrict__ col,
    const float* __restrict__ ew, const int* __restrict__ hist,
    const int* __restrict__ btot, int2* __restrict__ payload,
    int E, int nbuck, int epb)
{
    __shared__ int bins[1024];
    __shared__ int base[1024];
    __shared__ int cur[1024];
    __shared__ int hbase[1024];
    __shared__ int bbl[1024];
    __shared__ int2 lpay[EPB_CAP];      // 25.6 KB
    __shared__ ushort karr[EPB_CAP];    // 6.4 KB
    __shared__ int wsum[8];

    int t = threadIdx.x, b = blockIdx.x;
    int lane = t & 63, wid = t >> 6;

    spine_scan(btot, bbl, wsum, nbuck, t);

    for (int i = t; i < 1024; i += 512) {
        int hb = (i < nbuck) ? hist[b * nbuck + i] : 0;
        int hn = 0;
        if (i < nbuck)
            hn = (b < NPART - 1) ? hist[(b + 1) * nbuck + i] : btot[i];
        hbase[i] = hb;
        bins[i] = hn - hb;
    }
    __syncthreads();

    {
        int a = bins[2 * t], b2 = bins[2 * t + 1];
        int s = a + b2;
        int x = s;
        #pragma unroll
        for (int d = 1; d < 64; d <<= 1) {
            int y = __shfl_up(x, d, 64);
            if (lane >= d) x += y;
        }
        if (lane == 63) wsum[wid] = x;
        __syncthreads();
        if (t == 0) {
            int run = 0;
            #pragma unroll
            for (int w = 0; w < 8; ++w) { int z = wsum[w]; wsum[w] = run; run += z; }
        }
        __syncthreads();
        int excl = x - s + wsum[wid];
        base[2 * t] = excl;
        base[2 * t + 1] = excl + a;
        cur[2 * t] = excl;
        cur[2 * t + 1] = excl + a;
    }
    __syncthreads();

    int e0 = b * epb;
    int e1 = min(e0 + epb, E);
    for (int e = e0 + t; e < e1; e += 512) {
        int c = col[e];
        int k = c >> BSHIFT;
        int pos = atomicAdd(&cur[k], 1);
        lpay[pos] = make_int2(row[e] | ((c & (BN - 1)) << 20),
                              __float_as_int(ew[e]));
        karr[pos] = (ushort)k;
    }
    __syncthreads();

    int tot = e1 - e0;
    for (int i = t; i < tot; i += 512) {
        int k = karr[i];
        int dst = bbl[k] + hbase[k] + (i - base[k]);
        payload[dst] = lpay[i];
    }
}

// ---- Kernel 5: deg_bins — per-bucket weighted degree -> dinv, bin counts --
__global__ __launch_bounds__(512) void deg_bins_kernel(
    const int2* __restrict__ payload, const int* __restrict__ btot,
    float* __restrict__ dinv, int* __restrict__ binsg, int N, int nbuck)
{
    __shared__ int bbl[1024];
    __shared__ int wsum[8];
    __shared__ int bin[BN];
    __shared__ float degl[BN];
    int t = threadIdx.x, k = blockIdx.x;

    spine_scan(btot, bbl, wsum, nbuck, t);
    if (t < BN) { bin[t] = 0; degl[t] = 0.f; }
    __syncthreads();

    int e0 = bbl[k], e1 = e0 + btot[k];
    for (int e = e0 + t; e < e1; e += 512) {
        int2 p = payload[e];
        int ld = p.x >> 20;
        atomicAdd(&bin[ld], 1);
        atomicAdd(&degl[ld], __int_as_float(p.y));
    }
    __syncthreads();

    if (t < BN) {
        int n = k * BN + t;
        if (n < N) dinv[n] = rsqrtf(degl[t] + 1.0f);   // +1 self-loop weight
        binsg[k * BN + t] = bin[t];
    }
}

// ---- Kernel 6: Xw' = bf16( dinv ⊙ (X @ W) )  (64 rows/block, 512 thr) -----
__global__ __launch_bounds__(512) void gemm_xw_kernel(
    const float* __restrict__ X, const float* __restrict__ W,
    const float* __restrict__ dinv, ushort* __restrict__ Y, int N)
{
    __shared__ float Wl[C * C];         // 16 KB
    __shared__ float xl[64][C];         // 16 KB
    int t = threadIdx.x;
    #pragma unroll
    for (int i = 0; i < 2; ++i)
        *(float4*)(Wl + 4 * (t + i * 512)) = *(const float4*)(W + 4 * (t + i * 512));

    int n0 = blockIdx.x * 64;
    #pragma unroll
    for (int i = 0; i < 2; ++i) {
        int idx = t + i * 512;            // 0..1023 : (row, float4-group)
        int rr = idx >> 4, cc = (idx & 15) << 2;
        int n = n0 + rr;
        float4 v = (n < N) ? *(const float4*)(X + (size_t)n * C + cc)
                           : make_float4(0.f, 0.f, 0.f, 0.f);
        *(float4*)(&xl[rr][cc]) = v;
    }
    __syncthreads();

    int c = t & 63, rb = (t >> 6) * 8;    // 8 waves x 8 rows = 64 rows
    float acc[8] = {0.f, 0.f, 0.f, 0.f, 0.f, 0.f, 0.f, 0.f};
    for (int k = 0; k < C; ++k) {
        float w = Wl[k * C + c];
        #pragma unroll
        for (int q = 0; q < 8; ++q) acc[q] = fmaf(xl[rb + q][k], w, acc[q]);
    }
    #pragma unroll
    for (int q = 0; q < 8; ++q) {
        int n = n0 + rb + q;
        if (n < N) Y[(size_t)n * C + c] = f2bf(acc[q] * dinv[n]);  // fold dinv[src]
    }
}

// ---- Kernel 7: sort_reduce — LDS counting sort + gather-reduce fused ------
__global__ __launch_bounds__(512) void sort_reduce_kernel(
    const int2* __restrict__ payload, const int* __restrict__ btot,
    const int* __restrict__ binsg, const float* __restrict__ dinv,
    const ushort* __restrict__ Xw,
    const float* __restrict__ ne, const float* __restrict__ ce,
    ushort* __restrict__ tmpb, int N, int nbuck)
{
    __shared__ int bbl[1024];
    __shared__ int wsum[8];
    __shared__ int bin[BN];
    __shared__ int bbase[BN];
    __shared__ int cur[BN];
    __shared__ float dinvl[BN];
    __shared__ int2 spay[SCAP];         // 32 KB
    int t = threadIdx.x, k = blockIdx.x;

    spine_scan(btot, bbl, wsum, nbuck, t);

    if (t < BN) {
        int n = k * BN + t;
        bin[t] = binsg[k * BN + t];
        dinvl[t] = (n < N) ? dinv[n] : 0.f;
    }
    __syncthreads();

    // exclusive scan of bin[0..127] in wave 0 (2 bins per lane)
    if (t < 64) {
        int a = bin[2 * t], b2 = bin[2 * t + 1];
        int s = a + b2;
        int x = s;
        #pragma unroll
        for (int d = 1; d < 64; d <<= 1) {
            int y = __shfl_up(x, d, 64);
            if (t >= d) x += y;
        }
        int excl = x - s;
        bbase[2 * t] = excl;
        bbase[2 * t + 1] = excl + a;
    }
    __syncthreads();
    if (t < BN) cur[t] = bbase[t];
    __syncthreads();

    int e0 = bbl[k];
    int tot = btot[k];
    bool fits = (tot <= SCAP);

    if (fits) {
        for (int e = e0 + t; e < e0 + tot; e += 512) {
            int2 p = payload[e];
            int ld = p.x >> 20;
            int pos = atomicAdd(&cur[ld], 1);
            spay[pos] = make_int2(p.x & RMASK,
                                  __float_as_int(__int_as_float(p.y) * dinvl[ld]));
        }
    }
    __syncthreads();

    // ---- reduce phase: 2 passes x 64 nodes, 8 lanes/node ----
    int lg = t >> 3;                      // node group 0..63
    int cs = (t & 7) << 3;                // channel offset (8 channels/lane)
    #pragma unroll
    for (int pass = 0; pass < 2; ++pass) {
        int ln = lg + pass * 64;          // local node 0..127
        int n = k * BN + ln;
        if (n >= N) continue;

        float a[8] = {0.f, 0.f, 0.f, 0.f, 0.f, 0.f, 0.f, 0.f};
        if (fits) {
            int j = bbase[ln], cnt = bin[ln];
            while (cnt >= 4) {
                int2 p0 = spay[j];
                int2 p1 = spay[j + 1];
                int2 p2 = spay[j + 2];
                int2 p3 = spay[j + 3];
                uint4 u0 = *(const uint4*)(Xw + (size_t)p0.x * C + cs);
                uint4 u1 = *(const uint4*)(Xw + (size_t)p1.x * C + cs);
                uint4 u2 = *(const uint4*)(Xw + (size_t)p2.x * C + cs);
                uint4 u3 = *(const uint4*)(Xw + (size_t)p3.x * C + cs);
                bf8fma(u0, __int_as_float(p0.y), a);
                bf8fma(u1, __int_as_float(p1.y), a);
                bf8fma(u2, __int_as_float(p2.y), a);
                bf8fma(u3, __int_as_float(p3.y), a);
                j += 4; cnt -= 4;
            }
            while (cnt > 0) {
                int2 pl = spay[j];
                uint4 u = *(const uint4*)(Xw + (size_t)pl.x * C + cs);
                bf8fma(u, __int_as_float(pl.y), a);
                ++j; --cnt;
            }
        } else {
            // correctness fallback (tot > SCAP never occurs for this data)
            for (int e = e0; e < e0 + tot; ++e) {
                int2 p = payload[e];
                if ((p.x >> 20) == ln) {
                    float nn = __int_as_float(p.y) * dinvl[ln];
                    uint4 u = *(const uint4*)(Xw + (size_t)(p.x & RMASK) * C + cs);
                    bf8fma(u, nn, a);
                }
            }
        }

        float di = dinvl[ln];
        size_t o = (size_t)n * C + cs;
        uint4 ux = *(const uint4*)(Xw + o);     // Xw' = dinv[n]*(X@W)[n]
        bf8fma(ux, di, a);
        const float4 nv0 = *(const float4*)(ne + o);
        const float4 nv1 = *(const float4*)(ne + o + 4);
        const float4 cv0 = *(const float4*)(ce + o);
        const float4 cv1 = *(const float4*)(ce + o + 4);
        a[0] += nv0.x + cv0.x;  a[1] += nv0.y + cv0.y;
        a[2] += nv0.z + cv0.z;  a[3] += nv0.w + cv0.w;
        a[4] += nv1.x + cv1.x;  a[5] += nv1.y + cv1.y;
        a[6] += nv1.z + cv1.z;  a[7] += nv1.w + cv1.w;

        uint4 w;
        w.x = (uint)f2bf(a[0]) | ((uint)f2bf(a[1]) << 16);
        w.y = (uint)f2bf(a[2]) | ((uint)f2bf(a[3]) << 16);
        w.z = (uint)f2bf(a[4]) | ((uint)f2bf(a[5]) << 16);
        w.w = (uint)f2bf(a[6]) | ((uint)f2bf(a[7]) << 16);
        *(uint4*)(tmpb + o) = w;
    }
}

// ---- Kernel 8: out = tmp @ fW^T + fb  (64 rows/block, 512 thr, bf16 in) ---
__global__ __launch_bounds__(512) void fusion_kernel(
    const ushort* __restrict__ tmpb, const float* __restrict__ fW,
    const float* __restrict__ fb, float* __restrict__ out, int N)
{
    __shared__ float Wt[C][C + 1];   // 16.25 KB, Wt[k][j] = fW[j*C+k]
    __shared__ float tl[64][C];      // 16 KB
    int t = threadIdx.x;
    #pragma unroll
    for (int i = 0; i < 8; ++i) {
        int idx = t + i * 512;
        Wt[idx & 63][idx >> 6] = fW[idx];
    }
    int n0 = blockIdx.x * 64;
    {
        int rr = t >> 3, cs = (t & 7) << 3;   // 512 thr x 8 ch = 64 rows
        int n = n0 + rr;
        uint4 u = (n < N) ? *(const uint4*)(tmpb + (size_t)n * C + cs)
                          : make_uint4(0u, 0u, 0u, 0u);
        tl[rr][cs + 0] = __uint_as_float(u.x << 16);
        tl[rr][cs + 1] = __uint_as_float(u.x & 0xffff0000u);
        tl[rr][cs + 2] = __uint_as_float(u.y << 16);
        tl[rr][cs + 3] = __uint_as_float(u.y & 0xffff0000u);
        tl[rr][cs + 4] = __uint_as_float(u.z << 16);
        tl[rr][cs + 5] = __uint_as_float(u.z & 0xffff0000u);
        tl[rr][cs + 6] = __uint_as_float(u.w << 16);
        tl[rr][cs + 7] = __uint_as_float(u.w & 0xffff0000u);
    }
    __syncthreads();

    int j = t & 63, rb = (t >> 6) * 8;        // 8 waves x 8 rows = 64 rows
    float bj = fb[j];
    float acc[8] = {bj, bj, bj, bj, bj, bj, bj, bj};
    for (int k = 0; k < C; ++k) {
        float w = Wt[k][j];
        #pragma unroll
        for (int q = 0; q < 8; ++q) acc[q] = fmaf(tl[rb + q][k], w, acc[q]);
    }
    #pragma unroll
    for (int q = 0; q < 8; ++q) {
        int n = n0 + rb + q;
        if (n < N) out[(size_t)n * C + j] = acc[q];
    }
}

extern "C" void kernel_launch(void* const* d_in, const int* in_sizes, int n_in,
                              void* d_out, int out_size, void* d_ws, size_t ws_size,
                              hipStream_t stream)
{
    const float* X        = (const float*)d_in[0];
    const int*   ei       = (const int*)d_in[1];
    const float* ew       = (const float*)d_in[2];
    const float* node_emb = (const float*)d_in[3];
    const float* com_emb  = (const float*)d_in[4];
    const float* cw       = (const float*)d_in[5];
    const float* w_ih_f   = (const float*)d_in[6];
    const float* b_ih_f   = (const float*)d_in[7];
    const float* b_hh_f   = (const float*)d_in[8];
    const float* w_ih_b   = (const float*)d_in[9];
    const float* b_ih_b   = (const float*)d_in[10];
    const float* b_hh_b   = (const float*)d_in[11];
    const float* fW       = (const float*)d_in[12];
    const float* fb       = (const float*)d_in[13];
    float* out = (float*)d_out;

    const int N = in_sizes[0] / C;
    const int E = in_sizes[2];
    const int* row = ei;               // edge_index[0]
    const int* col = ei + E;           // edge_index[1]
    const int nbuck = (N + BN - 1) / BN;        // 782 (<= 1024 by design)
    const int epb = (E + NPART - 1) / NPART;    // 3125 <= EPB_CAP

    // ---- workspace layout ----
    char* wsb = (char*)d_ws;
    size_t o = 0;
    auto alloc = [&](size_t bytes) { void* p = wsb + o; o = (o + bytes + 15) & ~(size_t)15; return p; };
    float* W     = (float*)alloc((size_t)C * C * sizeof(float));        // 16 KB
    float* dinv  = (float*)alloc((size_t)N * sizeof(float));            // 400 KB
    int*   btot  = (int*)  alloc((size_t)(nbuck + 1) * sizeof(int));    // 3 KB
    int*   binsg = (int*)  alloc((size_t)nbuck * BN * sizeof(int));     // 400 KB
    int2*  payload = (int2*)alloc((size_t)E * sizeof(int2));            // 12.8 MB
    int*   hist  = (int*)  alloc((size_t)NPART * nbuck * sizeof(int));  // 1.6 MB
    ushort* tmpb = (ushort*)alloc((size_t)N * C * sizeof(ushort));      // 12.8 MB
    ushort* Xw   = (ushort*)out;   // d_out holds bf16 Xw' until fusion overwrites

    lstm_w_kernel<<<C / LCOLS, 256, 0, stream>>>(
        cw, w_ih_f, b_ih_f, b_hh_f, w_ih_b, b_ih_b, b_hh_b, W);

    hist_kernel<<<NPART, 256, 0, stream>>>(col, hist, E, nbuck, epb);

    scan_blocks_kernel<<<nbuck, NPART, 0, stream>>>(hist, btot, nbuck);

    partition_kernel<<<NPART, 512, 0, stream>>>(
        row, col, ew, hist, btot, payload, E, nbuck, epb);

    deg_bins_kernel<<<nbuck, 512, 0, stream>>>(
        payload, btot, dinv, binsg, N, nbuck);

    gemm_xw_kernel<<<(N + 63) / 64, 512, 0, stream>>>(X, W, dinv, Xw, N);

    sort_reduce_kernel<<<nbuck, 512, 0, stream>>>(
        payload, btot, binsg, dinv, Xw, node_emb, com_emb, tmpb, N, nbuck);

    fusion_kernel<<<(N + 63) / 64, 512, 0, stream>>>(tmpb, fW, fb, out, N);
}

// Round 16
// 145.051 us; speedup vs baseline: 1.2945x; 1.0083x over previous
//
#include <hip/hip_runtime.h>
#include <math.h>

#define C 64
#define BN 128              // nodes per destination bucket
#define BSHIFT 7            // log2(BN)
#define NPART 512           // partition blocks
#define EPB_CAP 3200        // LDS staging capacity per partition block
#define SCAP 4096           // LDS staging capacity per sort bucket (mean 2046, ~45 sigma)
#define RMASK ((1 << 20) - 1)
#define LCOLS 4             // output columns per LSTM block

typedef unsigned int uint;
typedef unsigned short ushort;

__device__ __forceinline__ float sigf(float x) { return 1.0f / (1.0f + __expf(-x)); }

// round-to-nearest-even f32 -> bf16 bits (values are finite, no NaN handling)
__device__ __forceinline__ ushort f2bf(float f) {
    uint u = __float_as_uint(f);
    return (ushort)((u + 0x7fffu + ((u >> 16) & 1u)) >> 16);
}

// fma 8 packed bf16 (uint4) into acc[8]
__device__ __forceinline__ void bf8fma(uint4 u, float nn, float* a) {
    a[0] = fmaf(__uint_as_float(u.x << 16),          nn, a[0]);
    a[1] = fmaf(__uint_as_float(u.x & 0xffff0000u),  nn, a[1]);
    a[2] = fmaf(__uint_as_float(u.y << 16),          nn, a[2]);
    a[3] = fmaf(__uint_as_float(u.y & 0xffff0000u),  nn, a[3]);
    a[4] = fmaf(__uint_as_float(u.z << 16),          nn, a[4]);
    a[5] = fmaf(__uint_as_float(u.z & 0xffff0000u),  nn, a[5]);
    a[6] = fmaf(__uint_as_float(u.w << 16),          nn, a[6]);
    a[7] = fmaf(__uint_as_float(u.w & 0xffff0000u),  nn, a[7]);
}

// in-LDS spine: bbl[0..nbuck-1] = exclusive scan of btot (512 threads, 2/thread)
__device__ __forceinline__ void spine_scan(
    const int* __restrict__ btot, int* bbl, int* wsum, int nbuck, int t)
{
    int lane = t & 63, wid = t >> 6;
    int i0 = 2 * t, i1 = 2 * t + 1;
    int v0 = (i0 < nbuck) ? btot[i0] : 0;
    int v1 = (i1 < nbuck) ? btot[i1] : 0;
    int s = v0 + v1;
    int x = s;
    #pragma unroll
    for (int d = 1; d < 64; d <<= 1) {
        int y = __shfl_up(x, d, 64);
        if (lane >= d) x += y;
    }
    if (lane == 63) wsum[wid] = x;
    __syncthreads();
    if (t == 0) {
        int run = 0;
        #pragma unroll
        for (int w = 0; w < 8; ++w) { int z = wsum[w]; wsum[w] = run; run += z; }
    }
    __syncthreads();
    int excl = x - s + wsum[wid];
    bbl[i0] = excl;
    bbl[i1] = excl + v0;
}

// ---- Kernel 1: LSTM weight, LDS-cooperative (coalesced loads) -------------
__global__ __launch_bounds__(256) void lstm_w_kernel(
    const float* __restrict__ cw,
    const float* __restrict__ wf, const float* __restrict__ bif, const float* __restrict__ bhf,
    const float* __restrict__ wb, const float* __restrict__ bib, const float* __restrict__ bhb,
    float* __restrict__ W)
{
    __shared__ float cwl[C][C + 1];        // 16.25 KB
    __shared__ float wl[6][LCOLS][C + 1];  // ~6.1 KB
    int t = threadIdx.x, b = blockIdx.x;
    int c0 = b * LCOLS;

    for (int m = t; m < C * C; m += 256)
        cwl[m >> 6][m & 63] = cw[m];

    // gate row offsets within [4C, C] weights: i=0, g=2C, o=3C (f unused, c0=0)
    for (int m = t; m < 6 * LCOLS * C; m += 256) {
        int mat = m >> 8;               // /(LCOLS*C)=256
        int idx = m & 255;
        int col = idx >> 6, k = idx & 63;
        int gofs = (mat % 3 == 0) ? 0 : ((mat % 3 == 1) ? 2 * C : 3 * C);
        const float* src = (mat < 3) ? wf : wb;
        wl[mat][col][k] = src[(gofs + c0 + col) * C + k];
    }
    __syncthreads();

    int r = t >> 2, cl = t & 3;
    int c = c0 + cl;
    float zif = 0.f, zgf = 0.f, zof = 0.f, zib = 0.f, zgb = 0.f, zob = 0.f;
    #pragma unroll
    for (int k = 0; k < C; ++k) {
        float xv = cwl[r][k];
        zif = fmaf(xv, wl[0][cl][k], zif);
        zgf = fmaf(xv, wl[1][cl][k], zgf);
        zof = fmaf(xv, wl[2][cl][k], zof);
        zib = fmaf(xv, wl[3][cl][k], zib);
        zgb = fmaf(xv, wl[4][cl][k], zgb);
        zob = fmaf(xv, wl[5][cl][k], zob);
    }
    zif += bif[0 * C + c] + bhf[0 * C + c];
    zgf += bif[2 * C + c] + bhf[2 * C + c];
    zof += bif[3 * C + c] + bhf[3 * C + c];
    zib += bib[0 * C + c] + bhb[0 * C + c];
    zgb += bib[2 * C + c] + bhb[2 * C + c];
    zob += bib[3 * C + c] + bhb[3 * C + c];

    float cf = sigf(zif) * tanhf(zgf);
    float hf = sigf(zof) * tanhf(cf);
    float cb = sigf(zib) * tanhf(zgb);
    float hb = sigf(zob) * tanhf(cb);
    W[r * C + c] = fmaxf(hf, hb);
}

// ---- Kernel 2: per-block bucket histogram (LDS atomics only) --------------
__global__ __launch_bounds__(256) void hist_kernel(
    const int* __restrict__ col, int* __restrict__ hist,
    int E, int nbuck, int epb)
{
    __shared__ int h[1024];
    int t = threadIdx.x, b = blockIdx.x;
    for (int i = t; i < nbuck; i += 256) h[i] = 0;
    __syncthreads();
    int base = b * epb;
    int end = min(base + epb, E);
    for (int e = base + t; e < end; e += 256)
        atomicAdd(&h[col[e] >> BSHIFT], 1);
    __syncthreads();
    for (int i = t; i < nbuck; i += 256) hist[b * nbuck + i] = h[i];
}

// ---- Kernel 3: per-bucket exclusive scan over blocks (parallel) -----------
__global__ __launch_bounds__(512) void scan_blocks_kernel(
    int* __restrict__ hist, int* __restrict__ btot, int nbuck)
{
    __shared__ int wsum[8];
    int k = blockIdx.x;
    int b = threadIdx.x;
    int v = hist[b * nbuck + k];
    int lane = b & 63, wid = b >> 6;
    int x = v;
    #pragma unroll
    for (int d = 1; d < 64; d <<= 1) {
        int y = __shfl_up(x, d, 64);
        if (lane >= d) x += y;
    }
    if (lane == 63) wsum[wid] = x;
    __syncthreads();
    if (b == 0) {
        int run = 0;
        #pragma unroll
        for (int w = 0; w < 8; ++w) { int z = wsum[w]; wsum[w] = run; run += z; }
    }
    __syncthreads();
    int excl = x - v + wsum[wid];
    hist[b * nbuck + k] = excl;
    if (b == NPART - 1) btot[k] = excl + v;
}

// ---- Kernel 4: partition — no recount (bins derived from scanned hist) ----
__global__ __launch_bounds__(512) void partition_kernel(
    const int* __restrict__ row, const int* __restrict__ col,
    const float* __restrict__ ew, const int* __restrict__ hist,
    const int* __restrict__ btot, int2* __restrict__ payload,
    int E, int nbuck, int epb)
{
    __shared__ int bins[1024];
    __shared__ int base[1024];
    __shared__ int cur[1024];
    __shared__ int hbase[1024];
    __shared__ int bbl[1024];
    __shared__ int2 lpay[EPB_CAP];      // 25.6 KB
    __shared__ ushort karr[EPB_CAP];    // 6.4 KB
    __shared__ int wsum[8];

    int t = threadIdx.x, b = blockIdx.x;
    int lane = t & 63, wid = t >> 6;

    spine_scan(btot, bbl, wsum, nbuck, t);

    for (int i = t; i < 1024; i += 512) {
        int hb = (i < nbuck) ? hist[b * nbuck + i] : 0;
        int hn = 0;
        if (i < nbuck)
            hn = (b < NPART - 1) ? hist[(b + 1) * nbuck + i] : btot[i];
        hbase[i] = hb;
        bins[i] = hn - hb;
    }
    __syncthreads();

    {
        int a = bins[2 * t], b2 = bins[2 * t + 1];
        int s = a + b2;
        int x = s;
        #pragma unroll
        for (int d = 1; d < 64; d <<= 1) {
            int y = __shfl_up(x, d, 64);
            if (lane >= d) x += y;
        }
        if (lane == 63) wsum[wid] = x;
        __syncthreads();
        if (t == 0) {
            int run = 0;
            #pragma unroll
            for (int w = 0; w < 8; ++w) { int z = wsum[w]; wsum[w] = run; run += z; }
        }
        __syncthreads();
        int excl = x - s + wsum[wid];
        base[2 * t] = excl;
        base[2 * t + 1] = excl + a;
        cur[2 * t] = excl;
        cur[2 * t + 1] = excl + a;
    }
    __syncthreads();

    int e0 = b * epb;
    int e1 = min(e0 + epb, E);
    for (int e = e0 + t; e < e1; e += 512) {
        int c = col[e];
        int k = c >> BSHIFT;
        int pos = atomicAdd(&cur[k], 1);
        lpay[pos] = make_int2(row[e] | ((c & (BN - 1)) << 20),
                              __float_as_int(ew[e]));
        karr[pos] = (ushort)k;
    }
    __syncthreads();

    int tot = e1 - e0;
    for (int i = t; i < tot; i += 512) {
        int k = karr[i];
        int dst = bbl[k] + hbase[k] + (i - base[k]);
        payload[dst] = lpay[i];
    }
}

// ---- Kernel 5: deg_gemm — deg/bins for bucket k, then gemm for its rows ---
// Phase 1: weighted degree + bin counts for nodes [k*BN, k*BN+BN) (LDS).
// Phase 2: Xw'[n] = bf16( dinvl[n] * (X@W)[n] ) for those rows, dinv from LDS.
__global__ __launch_bounds__(512) void deg_gemm_kernel(
    const int2* __restrict__ payload, const int* __restrict__ btot,
    const float* __restrict__ X, const float* __restrict__ W,
    float* __restrict__ dinv, int* __restrict__ binsg,
    ushort* __restrict__ Y, int N, int nbuck)
{
    __shared__ int bbl[1024];
    __shared__ int wsum[8];
    __shared__ int bin[BN];
    __shared__ float degl[BN];
    __shared__ float dinvl[BN];
    __shared__ float Wl[C * C];         // 16 KB
    __shared__ float xl[64][C];         // 16 KB
    int t = threadIdx.x, k = blockIdx.x;

    spine_scan(btot, bbl, wsum, nbuck, t);
    if (t < BN) { bin[t] = 0; degl[t] = 0.f; }
    __syncthreads();

    int e0 = bbl[k], e1 = e0 + btot[k];
    for (int e = e0 + t; e < e1; e += 512) {
        int2 p = payload[e];
        int ld = p.x >> 20;
        atomicAdd(&bin[ld], 1);
        atomicAdd(&degl[ld], __int_as_float(p.y));
    }
    __syncthreads();

    if (t < BN) {
        int n = k * BN + t;
        float di = rsqrtf(degl[t] + 1.0f);   // +1 self-loop weight
        dinvl[t] = di;
        if (n < N) dinv[n] = di;             // sort_reduce reads this
        binsg[k * BN + t] = bin[t];
    }

    // stage W while phase-1 results settle
    #pragma unroll
    for (int i = 0; i < 2; ++i)
        *(float4*)(Wl + 4 * (t + i * 512)) = *(const float4*)(W + 4 * (t + i * 512));
    __syncthreads();

    // ---- phase 2: gemm for 2 chunks of 64 rows ----
    int c = t & 63, rb = (t >> 6) * 8;    // 8 waves x 8 rows = 64 rows
    #pragma unroll
    for (int chunk = 0; chunk < 2; ++chunk) {
        int n0 = k * BN + chunk * 64;
        #pragma unroll
        for (int i = 0; i < 2; ++i) {
            int idx = t + i * 512;            // 0..1023 : (row, float4-group)
            int rr = idx >> 4, cc = (idx & 15) << 2;
            int n = n0 + rr;
            float4 v = (n < N) ? *(const float4*)(X + (size_t)n * C + cc)
                               : make_float4(0.f, 0.f, 0.f, 0.f);
            *(float4*)(&xl[rr][cc]) = v;
        }
        __syncthreads();

        float acc[8] = {0.f, 0.f, 0.f, 0.f, 0.f, 0.f, 0.f, 0.f};
        for (int kk = 0; kk < C; ++kk) {
            float w = Wl[kk * C + c];
            #pragma unroll
            for (int q = 0; q < 8; ++q) acc[q] = fmaf(xl[rb + q][kk], w, acc[q]);
        }
        #pragma unroll
        for (int q = 0; q < 8; ++q) {
            int n = n0 + rb + q;
            if (n < N)
                Y[(size_t)n * C + c] = f2bf(acc[q] * dinvl[chunk * 64 + rb + q]);
        }
        __syncthreads();
    }
}

// ---- Kernel 6: sort_reduce — LDS counting sort + gather-reduce fused ------
__global__ __launch_bounds__(512) void sort_reduce_kernel(
    const int2* __restrict__ payload, const int* __restrict__ btot,
    const int* __restrict__ binsg, const float* __restrict__ dinv,
    const ushort* __restrict__ Xw,
    const float* __restrict__ ne, const float* __restrict__ ce,
    ushort* __restrict__ tmpb, int N, int nbuck)
{
    __shared__ int bbl[1024];
    __shared__ int wsum[8];
    __shared__ int bin[BN];
    __shared__ int bbase[BN];
    __shared__ int cur[BN];
    __shared__ float dinvl[BN];
    __shared__ int2 spay[SCAP];         // 32 KB
    int t = threadIdx.x, k = blockIdx.x;

    spine_scan(btot, bbl, wsum, nbuck, t);

    if (t < BN) {
        int n = k * BN + t;
        bin[t] = binsg[k * BN + t];
        dinvl[t] = (n < N) ? dinv[n] : 0.f;
    }
    __syncthreads();

    // exclusive scan of bin[0..127] in wave 0 (2 bins per lane)
    if (t < 64) {
        int a = bin[2 * t], b2 = bin[2 * t + 1];
        int s = a + b2;
        int x = s;
        #pragma unroll
        for (int d = 1; d < 64; d <<= 1) {
            int y = __shfl_up(x, d, 64);
            if (t >= d) x += y;
        }
        int excl = x - s;
        bbase[2 * t] = excl;
        bbase[2 * t + 1] = excl + a;
    }
    __syncthreads();
    if (t < BN) cur[t] = bbase[t];
    __syncthreads();

    int e0 = bbl[k];
    int tot = btot[k];
    bool fits = (tot <= SCAP);

    if (fits) {
        for (int e = e0 + t; e < e0 + tot; e += 512) {
            int2 p = payload[e];
            int ld = p.x >> 20;
            int pos = atomicAdd(&cur[ld], 1);
            spay[pos] = make_int2(p.x & RMASK,
                                  __float_as_int(__int_as_float(p.y) * dinvl[ld]));
        }
    }
    __syncthreads();

    // ---- reduce phase: 2 passes x 64 nodes, 8 lanes/node ----
    int lg = t >> 3;                      // node group 0..63
    int cs = (t & 7) << 3;                // channel offset (8 channels/lane)
    #pragma unroll
    for (int pass = 0; pass < 2; ++pass) {
        int ln = lg + pass * 64;          // local node 0..127
        int n = k * BN + ln;
        if (n >= N) continue;

        float a[8] = {0.f, 0.f, 0.f, 0.f, 0.f, 0.f, 0.f, 0.f};
        if (fits) {
            int j = bbase[ln], cnt = bin[ln];
            while (cnt >= 4) {
                int2 p0 = spay[j];
                int2 p1 = spay[j + 1];
                int2 p2 = spay[j + 2];
                int2 p3 = spay[j + 3];
                uint4 u0 = *(const uint4*)(Xw + (size_t)p0.x * C + cs);
                uint4 u1 = *(const uint4*)(Xw + (size_t)p1.x * C + cs);
                uint4 u2 = *(const uint4*)(Xw + (size_t)p2.x * C + cs);
                uint4 u3 = *(const uint4*)(Xw + (size_t)p3.x * C + cs);
                bf8fma(u0, __int_as_float(p0.y), a);
                bf8fma(u1, __int_as_float(p1.y), a);
                bf8fma(u2, __int_as_float(p2.y), a);
                bf8fma(u3, __int_as_float(p3.y), a);
                j += 4; cnt -= 4;
            }
            while (cnt > 0) {
                int2 pl = spay[j];
                uint4 u = *(const uint4*)(Xw + (size_t)pl.x * C + cs);
                bf8fma(u, __int_as_float(pl.y), a);
                ++j; --cnt;
            }
        } else {
            // correctness fallback (tot > SCAP never occurs for this data)
            for (int e = e0; e < e0 + tot; ++e) {
                int2 p = payload[e];
                if ((p.x >> 20) == ln) {
                    float nn = __int_as_float(p.y) * dinvl[ln];
                    uint4 u = *(const uint4*)(Xw + (size_t)(p.x & RMASK) * C + cs);
                    bf8fma(u, nn, a);
                }
            }
        }

        float di = dinvl[ln];
        size_t o = (size_t)n * C + cs;
        uint4 ux = *(const uint4*)(Xw + o);     // Xw' = dinv[n]*(X@W)[n]
        bf8fma(ux, di, a);
        const float4 nv0 = *(const float4*)(ne + o);
        const float4 nv1 = *(const float4*)(ne + o + 4);
        const float4 cv0 = *(const float4*)(ce + o);
        const float4 cv1 = *(const float4*)(ce + o + 4);
        a[0] += nv0.x + cv0.x;  a[1] += nv0.y + cv0.y;
        a[2] += nv0.z + cv0.z;  a[3] += nv0.w + cv0.w;
        a[4] += nv1.x + cv1.x;  a[5] += nv1.y + cv1.y;
        a[6] += nv1.z + cv1.z;  a[7] += nv1.w + cv1.w;

        uint4 w;
        w.x = (uint)f2bf(a[0]) | ((uint)f2bf(a[1]) << 16);
        w.y = (uint)f2bf(a[2]) | ((uint)f2bf(a[3]) << 16);
        w.z = (uint)f2bf(a[4]) | ((uint)f2bf(a[5]) << 16);
        w.w = (uint)f2bf(a[6]) | ((uint)f2bf(a[7]) << 16);
        *(uint4*)(tmpb + o) = w;
    }
}

// ---- Kernel 7: out = tmp @ fW^T + fb  (64 rows/block, 512 thr, bf16 in) ---
__global__ __launch_bounds__(512) void fusion_kernel(
    const ushort* __restrict__ tmpb, const float* __restrict__ fW,
    const float* __restrict__ fb, float* __restrict__ out, int N)
{
    __shared__ float Wt[C][C + 1];   // 16.25 KB, Wt[k][j] = fW[j*C+k]
    __shared__ float tl[64][C];      // 16 KB
    int t = threadIdx.x;
    #pragma unroll
    for (int i = 0; i < 8; ++i) {
        int idx = t + i * 512;
        Wt[idx & 63][idx >> 6] = fW[idx];
    }
    int n0 = blockIdx.x * 64;
    {
        int rr = t >> 3, cs = (t & 7) << 3;   // 512 thr x 8 ch = 64 rows
        int n = n0 + rr;
        uint4 u = (n < N) ? *(const uint4*)(tmpb + (size_t)n * C + cs)
                          : make_uint4(0u, 0u, 0u, 0u);
        tl[rr][cs + 0] = __uint_as_float(u.x << 16);
        tl[rr][cs + 1] = __uint_as_float(u.x & 0xffff0000u);
        tl[rr][cs + 2] = __uint_as_float(u.y << 16);
        tl[rr][cs + 3] = __uint_as_float(u.y & 0xffff0000u);
        tl[rr][cs + 4] = __uint_as_float(u.z << 16);
        tl[rr][cs + 5] = __uint_as_float(u.z & 0xffff0000u);
        tl[rr][cs + 6] = __uint_as_float(u.w << 16);
        tl[rr][cs + 7] = __uint_as_float(u.w & 0xffff0000u);
    }
    __syncthreads();

    int j = t & 63, rb = (t >> 6) * 8;        // 8 waves x 8 rows = 64 rows
    float bj = fb[j];
    float acc[8] = {bj, bj, bj, bj, bj, bj, bj, bj};
    for (int k = 0; k < C; ++k) {
        float w = Wt[k][j];
        #pragma unroll
        for (int q = 0; q < 8; ++q) acc[q] = fmaf(tl[rb + q][k], w, acc[q]);
    }
    #pragma unroll
    for (int q = 0; q < 8; ++q) {
        int n = n0 + rb + q;
        if (n < N) out[(size_t)n * C + j] = acc[q];
    }
}

extern "C" void kernel_launch(void* const* d_in, const int* in_sizes, int n_in,
                              void* d_out, int out_size, void* d_ws, size_t ws_size,
                              hipStream_t stream)
{
    const float* X        = (const float*)d_in[0];
    const int*   ei       = (const int*)d_in[1];
    const float* ew       = (const float*)d_in[2];
    const float* node_emb = (const float*)d_in[3];
    const float* com_emb  = (const float*)d_in[4];
    const float* cw       = (const float*)d_in[5];
    const float* w_ih_f   = (const float*)d_in[6];
    const float* b_ih_f   = (const float*)d_in[7];
    const float* b_hh_f   = (const float*)d_in[8];
    const float* w_ih_b   = (const float*)d_in[9];
    const float* b_ih_b   = (const float*)d_in[10];
    const float* b_hh_b   = (const float*)d_in[11];
    const float* fW       = (const float*)d_in[12];
    const float* fb       = (const float*)d_in[13];
    float* out = (float*)d_out;

    const int N = in_sizes[0] / C;
    const int E = in_sizes[2];
    const int* row = ei;               // edge_index[0]
    const int* col = ei + E;           // edge_index[1]
    const int nbuck = (N + BN - 1) / BN;        // 782 (<= 1024 by design)
    const int epb = (E + NPART - 1) / NPART;    // 3125 <= EPB_CAP

    // ---- workspace layout ----
    char* wsb = (char*)d_ws;
    size_t o = 0;
    auto alloc = [&](size_t bytes) { void* p = wsb + o; o = (o + bytes + 15) & ~(size_t)15; return p; };
    float* W     = (float*)alloc((size_t)C * C * sizeof(float));        // 16 KB
    float* dinv  = (float*)alloc((size_t)N * sizeof(float));            // 400 KB
    int*   btot  = (int*)  alloc((size_t)(nbuck + 1) * sizeof(int));    // 3 KB
    int*   binsg = (int*)  alloc((size_t)nbuck * BN * sizeof(int));     // 400 KB
    int2*  payload = (int2*)alloc((size_t)E * sizeof(int2));            // 12.8 MB
    int*   hist  = (int*)  alloc((size_t)NPART * nbuck * sizeof(int));  // 1.6 MB
    ushort* tmpb = (ushort*)alloc((size_t)N * C * sizeof(ushort));      // 12.8 MB
    ushort* Xw   = (ushort*)out;   // d_out holds bf16 Xw' until fusion overwrites

    lstm_w_kernel<<<C / LCOLS, 256, 0, stream>>>(
        cw, w_ih_f, b_ih_f, b_hh_f, w_ih_b, b_ih_b, b_hh_b, W);

    hist_kernel<<<NPART, 256, 0, stream>>>(col, hist, E, nbuck, epb);

    scan_blocks_kernel<<<nbuck, NPART, 0, stream>>>(hist, btot, nbuck);

    partition_kernel<<<NPART, 512, 0, stream>>>(
        row, col, ew, hist, btot, payload, E, nbuck, epb);

    deg_gemm_kernel<<<nbuck, 512, 0, stream>>>(
        payload, btot, X, W, dinv, binsg, Xw, N, nbuck);

    sort_reduce_kernel<<<nbuck, 512, 0, stream>>>(
        payload, btot, binsg, dinv, Xw, node_emb, com_emb, tmpb, N, nbuck);

    fusion_kernel<<<(N + 63) / 64, 512, 0, stream>>>(tmpb, fW, fb, out, N);
}